// Round 2
// baseline (177.808 us; speedup 1.0000x reference)
//
#include <hip/hip_runtime.h>
#include <math.h>

#define BB 8
#define PP 2048
#define VV 2562
#define NV 8192
#define FF 16384
#define EPSF 1e-12f

// ---------------------------------------------------------------------------
// Kernel 1: per-face normals scatter-added to per-vertex accumulators.
// One thread per face. Random vertex indices -> global atomicAdd (avg ~6
// adds per slot; low contention).
// ---------------------------------------------------------------------------
__global__ __launch_bounds__(256) void face_normals_kernel(
    const float* __restrict__ gtv,   // (B, NV, 3)
    const int*   __restrict__ faces, // (B, FF, 3) int32
    float*       __restrict__ nrm)   // (B, NV, 3) accumulators (pre-zeroed)
{
    int t = blockIdx.x * blockDim.x + threadIdx.x;
    if (t >= BB * FF) return;
    int b = t / FF;
    const int* fc = faces + (size_t)t * 3;
    int i0 = fc[0], i1 = fc[1], i2 = fc[2];

    const float* vb = gtv + (size_t)b * NV * 3;
    float v0x = vb[i0*3+0], v0y = vb[i0*3+1], v0z = vb[i0*3+2];
    float v1x = vb[i1*3+0], v1y = vb[i1*3+1], v1z = vb[i1*3+2];
    float v2x = vb[i2*3+0], v2y = vb[i2*3+1], v2z = vb[i2*3+2];

    float e1x = v1x - v0x, e1y = v1y - v0y, e1z = v1z - v0z;
    float e2x = v2x - v0x, e2y = v2y - v0y, e2z = v2z - v0z;

    float fnx = e1y * e2z - e1z * e2y;
    float fny = e1z * e2x - e1x * e2z;
    float fnz = e1x * e2y - e1y * e2x;

    float* nb = nrm + (size_t)b * NV * 3;
    atomicAdd(&nb[i0*3+0], fnx); atomicAdd(&nb[i0*3+1], fny); atomicAdd(&nb[i0*3+2], fnz);
    atomicAdd(&nb[i1*3+0], fnx); atomicAdd(&nb[i1*3+1], fny); atomicAdd(&nb[i1*3+2], fnz);
    atomicAdd(&nb[i2*3+0], fnx); atomicAdd(&nb[i2*3+1], fny); atomicAdd(&nb[i2*3+2], fnz);
}

// ---------------------------------------------------------------------------
// Kernel 2: main NN + loss. One wave (64 lanes) handles 4 query points.
// Lanes split the reference set (lane l scans refs l, l+64, ...), each ref
// load amortized over the wave's 4 points. Butterfly shfl argmin reduction
// (first-index tie-break). Lane 0 gathers + computes the 4 loss terms;
// block writes one partial sum.
// 4 waves/block, 16 points/block -> 1024 blocks for 8*2048 points.
// ---------------------------------------------------------------------------
__global__ __launch_bounds__(256) void nn_loss_kernel(
    const float* __restrict__ pp,   // (B, P, 3)  pred_points
    const float* __restrict__ pv,   // (B, V, 3)  pred_vertices
    const float* __restrict__ gtv,  // (B, NV, 3) gt_vertices
    const float* __restrict__ nrm,  // (B, NV, 3) gt vertex normals
    float*       __restrict__ partial) // (gridDim.x)
{
    const int lane = threadIdx.x & 63;
    const int wave = threadIdx.x >> 6;          // 0..3
    const int gw   = blockIdx.x * 4 + wave;     // global wave id 0..4095
    const int b    = gw >> 9;                   // 512 waves per batch
    const int p0   = (gw & 511) * 4;            // first of 4 points

    // Load this wave's 4 query points (wave-uniform; L1 broadcast).
    float px[4], py[4], pz[4];
    const float* ppb = pp + ((size_t)b * PP + p0) * 3;
#pragma unroll
    for (int j = 0; j < 4; ++j) {
        px[j] = ppb[j*3+0]; py[j] = ppb[j*3+1]; pz[j] = ppb[j*3+2];
    }

    // ---- scan gt_vertices (8192 = 128 iters * 64 lanes, no tail) ----
    float bd[4]; int bi[4];
#pragma unroll
    for (int j = 0; j < 4; ++j) { bd[j] = INFINITY; bi[j] = 0; }

    const float* gvb = gtv + (size_t)b * NV * 3;
    for (int i = 0; i < NV / 64; ++i) {
        int r = lane + i * 64;
        float rx = gvb[r*3+0], ry = gvb[r*3+1], rz = gvb[r*3+2];
#pragma unroll
        for (int j = 0; j < 4; ++j) {
            float dx = px[j] - rx, dy = py[j] - ry, dz = pz[j] - rz;
            float d = fmaf(dx, dx, fmaf(dy, dy, dz * dz));
            bool take = d < bd[j];           // strict <: keeps lowest idx per lane
            bd[j] = take ? d : bd[j];
            bi[j] = take ? r : bi[j];
        }
    }

    int gt_idx[4];
#pragma unroll
    for (int j = 0; j < 4; ++j) {
        float d = bd[j]; int idx = bi[j];
#pragma unroll
        for (int off = 32; off; off >>= 1) {
            float od = __shfl_xor(d, off);
            int   oi = __shfl_xor(idx, off);
            if (od < d || (od == d && oi < idx)) { d = od; idx = oi; }
        }
        gt_idx[j] = idx;   // uniform across wave after butterfly
    }

    // ---- scan pred_vertices (2562: 41 iters, guard the tail) ----
#pragma unroll
    for (int j = 0; j < 4; ++j) { bd[j] = INFINITY; bi[j] = 0; }

    const float* pvb = pv + (size_t)b * VV * 3;
    for (int i = 0; i < (VV + 63) / 64; ++i) {
        int r = lane + i * 64;
        int rc = (r < VV) ? r : (VV - 1);
        float rx = pvb[rc*3+0], ry = pvb[rc*3+1], rz = pvb[rc*3+2];
#pragma unroll
        for (int j = 0; j < 4; ++j) {
            float dx = px[j] - rx, dy = py[j] - ry, dz = pz[j] - rz;
            float d = fmaf(dx, dx, fmaf(dy, dy, dz * dz));
            d = (r < VV) ? d : INFINITY;
            bool take = d < bd[j];
            bd[j] = take ? d : bd[j];
            bi[j] = take ? r : bi[j];
        }
    }

    int pr_idx[4];
#pragma unroll
    for (int j = 0; j < 4; ++j) {
        float d = bd[j]; int idx = bi[j];
#pragma unroll
        for (int off = 32; off; off >>= 1) {
            float od = __shfl_xor(d, off);
            int   oi = __shfl_xor(idx, off);
            if (od < d || (od == d && oi < idx)) { d = od; idx = oi; }
        }
        pr_idx[j] = idx;
    }

    // ---- loss terms (lane 0 of each wave; 4 small gathers) ----
    __shared__ float wsum[4];
    if (lane == 0) {
        const float* nb = nrm + (size_t)b * NV * 3;
        float s = 0.f;
#pragma unroll
        for (int j = 0; j < 4; ++j) {
            int vi = pr_idx[j];
            float ex = px[j] - pvb[vi*3+0];
            float ey = py[j] - pvb[vi*3+1];
            float ez = pz[j] - pvb[vi*3+2];
            float el = fmaxf(sqrtf(fmaf(ex, ex, fmaf(ey, ey, ez * ez))), EPSF);

            int ni = gt_idx[j];
            float nx = nb[ni*3+0];
            float ny = nb[ni*3+1];
            float nz = nb[ni*3+2];
            float nl = fmaxf(sqrtf(fmaf(nx, nx, fmaf(ny, ny, nz * nz))), EPSF);

            float dot = fmaf(ex, nx, fmaf(ey, ny, ez * nz));
            s += fabsf(dot / (el * nl));
        }
        wsum[wave] = s;
    }
    __syncthreads();
    if (threadIdx.x == 0)
        partial[blockIdx.x] = wsum[0] + wsum[1] + wsum[2] + wsum[3];
}

// ---------------------------------------------------------------------------
// Kernel 3: reduce 1024 partials -> mean -> out[0]
// ---------------------------------------------------------------------------
__global__ __launch_bounds__(256) void reduce_kernel(
    const float* __restrict__ partial, float* __restrict__ out, int n)
{
    int t = threadIdx.x;
    float s = 0.f;
    for (int i = t; i < n; i += 256) s += partial[i];
#pragma unroll
    for (int off = 32; off; off >>= 1) s += __shfl_xor(s, off);
    __shared__ float ws[4];
    if ((t & 63) == 0) ws[t >> 6] = s;
    __syncthreads();
    if (t == 0) out[0] = (ws[0] + ws[1] + ws[2] + ws[3]) / (float)(BB * PP);
}

// ---------------------------------------------------------------------------
extern "C" void kernel_launch(void* const* d_in, const int* in_sizes, int n_in,
                              void* d_out, int out_size, void* d_ws, size_t ws_size,
                              hipStream_t stream) {
    const float* pp    = (const float*)d_in[0];  // pred_points   (8,2048,3)
    const float* pv    = (const float*)d_in[1];  // pred_vertices (8,2562,3)
    const float* gtv   = (const float*)d_in[2];  // gt_vertices   (8,8192,3)
    const int*   faces = (const int*)d_in[3];    // gt_faces      (8,16384,3)
    float* out = (float*)d_out;

    float* nrm     = (float*)d_ws;                                   // 786432 B
    float* partial = (float*)((char*)d_ws + (size_t)BB*NV*3*sizeof(float)); // 4 KB

    // Zero the normal accumulators (ws is poisoned 0xAA before every launch).
    hipMemsetAsync(nrm, 0, (size_t)BB * NV * 3 * sizeof(float), stream);

    face_normals_kernel<<<(BB * FF + 255) / 256, 256, 0, stream>>>(gtv, faces, nrm);

    const int nblocks = (BB * PP) / 16;  // 1024: 4 waves/block * 4 points/wave
    nn_loss_kernel<<<nblocks, 256, 0, stream>>>(pp, pv, gtv, nrm, partial);

    reduce_kernel<<<1, 256, 0, stream>>>(partial, out, nblocks);
}